// Round 3
// baseline (373.911 us; speedup 1.0000x reference)
//
#include <hip/hip_runtime.h>

// CombinedActorModel R9: R8 + explicit occupancy declaration so the weight
// fragments actually stay in VGPRs.
// R8 post-mortem: VGPR_Count stayed 76 (< the 84 needed for F[21]) with the
// asm pin -- the default __launch_bounds__(256) heuristic budgeted ~76 VGPRs
// and spilled/re-loaded the fragments every tile. Fix: __launch_bounds__(256,4)
// = 4 waves/SIMD = 128-VGPR cap (the same occupancy bin we were already in),
// giving the allocator room for 84 frag regs + working set.
// Also TPB 16->8 (grid 2048): staggered block starts break the wave convoy on
// vmcnt waits and shorten the tail. Everything else identical to R8.

typedef _Float16 half8  __attribute__((ext_vector_type(8)));
typedef float    floatx4 __attribute__((ext_vector_type(4)));

#define NFRAG 21                    // 3 actors * (4 stage1 + 2 stage2 + 1 stage3)
#define FRAG_HALFS (NFRAG * 512)    // 10752 halfs = 21504 B
#define TPB 8                       // 64-elem tiles per block

__global__ __launch_bounds__(256) void prep_frags(
    const float* __restrict__ Wmx, const float* __restrict__ bmx,
    const float* __restrict__ Wnx, const float* __restrict__ bnx,
    const float* __restrict__ Wmy, const float* __restrict__ bmy,
    const float* __restrict__ Wny, const float* __restrict__ bny,
    const float* __restrict__ Wmz, const float* __restrict__ bmz,
    const float* __restrict__ Wnz, const float* __restrict__ bnz,
    const float* __restrict__ Wlin, const float* __restrict__ blin,
    const float* __restrict__ Wout, const float* __restrict__ bout,
    _Float16* __restrict__ frag)
{
    int i = threadIdx.x + blockIdx.x * blockDim.x;
    if (i >= FRAG_HALFS) return;
    int f = i >> 9, rem = i & 511;
    int lane = rem >> 3, j = rem & 7;
    int q = lane >> 4, m = lane & 15;
    int a = f / 7, idx = f % 7;
    float v = 0.f;
    if (idx < 4) {
        // stage1 A-frag: rows = stage1 cols c, k = feature (standard 8q+j);
        // bias folded at k==27 (B operand supplies 1.0 there).
        int c = m + ((idx & 1) ? 16 : 0);
        int k = 8 * q + j;
        bool npart = (idx >= 2);
        if (c < 10) {
            if (!npart) { if (k < 6)             v = Wmx[(a*10 + c)*6 + k];
                          else if (k == 27)      v = bmx[a*10 + c]; }
            else        { if (k >= 6 && k < 9)   v = Wnx[(a*10 + c)*3 + (k-6)];
                          else if (k == 27)      v = bnx[a*10 + c]; }
        } else if (c < 20) {
            if (!npart) { if (k >= 9 && k < 15)  v = Wmy[(a*10 + c-10)*6 + (k-9)];
                          else if (k == 27)      v = bmy[a*10 + c-10]; }
            else        { if (k >= 15 && k < 18) v = Wny[(a*10 + c-10)*3 + (k-15)];
                          else if (k == 27)      v = bny[a*10 + c-10]; }
        } else if (c < 25) {
            if (!npart) { if (k >= 18 && k < 24) v = Wmz[(a*5 + c-20)*6 + (k-18)];
                          else if (k == 27)      v = bmz[a*5 + c-20]; }
            else        { if (k >= 24 && k < 27) v = Wnz[(a*5 + c-20)*3 + (k-24)];
                          else if (k == 27)      v = bnz[a*5 + c-20]; }
        }
    } else if (idx < 6) {
        // stage2 A-frag: rows = o, k permuted by sigma; bias at kc==25
        int o  = m + ((idx == 5) ? 16 : 0);
        int kc = 16 * (j >> 2) + 4 * q + (j & 3);   // sigma(q,j)
        if (o < 25) {
            if (kc < 25)       v = Wlin[(a*25 + o)*25 + kc];
            else if (kc == 25) v = blin[a*25 + o];
        }
    } else {
        // stage3 A-frag: rows = ch, k permuted by sigma; bias at ko==25
        int ko = 16 * (j >> 2) + 4 * q + (j & 3);
        if (m < 10) {
            if (ko < 25)       v = Wout[(a*15 + m)*25 + ko];
            else if (ko == 25) v = bout[a*15 + m];
        }
    }
    frag[(size_t)f * 512 + lane * 8 + j] = (_Float16)v;
}

__global__ __launch_bounds__(256, 4) void actor_mfma(
    const float* __restrict__ spatial,
    const _Float16* __restrict__ frag,
    float* __restrict__ out)
{
    __shared__ float lds_o[4 * 144];   // per-wave output compaction scratch

    const int t = threadIdx.x;
    const int lane = t & 63, w = t >> 6;
    const int q = lane >> 4, e = lane & 15;
    const size_t b0 = (size_t)blockIdx.x * (64 * TPB);

    // ---- weight fragments: global->VGPR once per block, then PINNED so the
    // compiler cannot sink/rematerialize the loads into the tile loop.
    half8 F[NFRAG];
    #pragma unroll
    for (int f = 0; f < NFRAG; ++f)
        F[f] = *(const half8*)(frag + (size_t)f * 512 + lane * 8);
    #pragma unroll
    for (int f = 0; f < NFRAG; ++f)
        asm volatile("" : "+v"(F[f]));

    const float* sbase = spatial + (b0 + (size_t)(w * 16 + e)) * 27 + 8 * q;
    float* const ldso = lds_o + w * 144;
    const floatx4 z = {0.f, 0.f, 0.f, 0.f};

    auto loadT = [&](float (&dst)[8], int tt) {
        const float* s_ = sbase + (size_t)tt * (64 * 27);
        #pragma unroll
        for (int j = 0; j < 8; ++j) {
            int k = 8 * q + j;
            float v = (k == 27) ? 1.f : 0.f;   // bias slot; k>27 -> 0
            if (k < 27) v = s_[j];
            dst[j] = v;
        }
    };

    auto tileCompute = [&](const float (&cur)[8], int tt) {
        half8 Bs;
        #pragma unroll
        for (int j = 0; j < 8; ++j) Bs[j] = (_Float16)cur[j];

        floatx4 oacc[3];
        #pragma unroll
        for (int a = 0; a < 3; ++a) {
            const int fb = a * 7;
            // stage1: D[c][e]; narrow transient pressure: finish P.lo from
            // M0/N0 before computing M1/N1.
            half8 P;
            {
                floatx4 M0 = __builtin_amdgcn_mfma_f32_16x16x32_f16(F[fb+0], Bs, z, 0,0,0);
                floatx4 N0 = __builtin_amdgcn_mfma_f32_16x16x32_f16(F[fb+2], Bs, z, 0,0,0);
                #pragma unroll
                for (int r = 0; r < 4; ++r) P[r] = (_Float16)(M0[r] * N0[r]);
            }
            {
                floatx4 M1 = __builtin_amdgcn_mfma_f32_16x16x32_f16(F[fb+1], Bs, z, 0,0,0);
                floatx4 N1 = __builtin_amdgcn_mfma_f32_16x16x32_f16(F[fb+3], Bs, z, 0,0,0);
                #pragma unroll
                for (int r = 0; r < 4; ++r) P[4 + r] = (_Float16)(M1[r] * N1[r]);
            }
            // sigma-packed slot kc=25 (q=2,j=5) carries the stage2 bias col
            if (q == 2) P[5] = (_Float16)1.f;

            // stage2: D[o][e] (Wlin frag sigma-packed, bias at kc=25)
            floatx4 H0 = __builtin_amdgcn_mfma_f32_16x16x32_f16(F[fb+4], P, z, 0,0,0);
            floatx4 H1 = __builtin_amdgcn_mfma_f32_16x16x32_f16(F[fb+5], P, z, 0,0,0);

            // softsign -> sigma-packed B operand for stage3; bias column = 1.0
            half8 Hh;
            #pragma unroll
            for (int r = 0; r < 4; ++r) {
                float v0 = H0[r];
                Hh[r]     = (_Float16)(v0 * __builtin_amdgcn_rcpf(1.0f + fabsf(v0)));
                float v1 = H1[r];
                Hh[4 + r] = (_Float16)(v1 * __builtin_amdgcn_rcpf(1.0f + fabsf(v1)));
            }
            if (q == 2) Hh[5] = (_Float16)1.f;

            // stage3: D[ch][e]; lane (e,q) reg r holds ch = 4q+r (gate ch9 @ q=2,r=1)
            oacc[a] = __builtin_amdgcn_mfma_f32_16x16x32_f16(F[fb+6], Hh, z, 0,0,0);
        }

        // ---- epilogue: softmax over actors of ch9, weighted sum of ch0..8
        const int src9 = 32 + e;   // lane (e, q=2); its reg1 = ch9
        float g0 = __shfl(oacc[0][1], src9, 64);
        float g1 = __shfl(oacc[1][1], src9, 64);
        float g2 = __shfl(oacc[2][1], src9, 64);
        float mx = fmaxf(g0, fmaxf(g1, g2));
        float e0 = __expf(g0 - mx);
        float e1 = __expf(g1 - mx);
        float e2 = __expf(g2 - mx);
        float inv = __builtin_amdgcn_rcpf(e0 + e1 + e2);
        e0 *= inv; e1 *= inv; e2 *= inv;

        float res[4];
        #pragma unroll
        for (int r = 0; r < 4; ++r)
            res[r] = oacc[0][r] * e0 + oacc[1][r] * e1 + oacc[2][r] * e2;

        // ---- compact to this wave's scratch, coalesced float4 store
        if (q < 2) {
            #pragma unroll
            for (int r = 0; r < 4; ++r) ldso[e * 9 + 4 * q + r] = res[r];
        } else if (q == 2) {
            ldso[e * 9 + 8] = res[0];
        }
        // same-wave DS ordering: writes retire before the reads below issue
        if (lane < 36) {
            float4 v = *(const float4*)(ldso + lane * 4);
            *(float4*)(out + (b0 + (size_t)tt * 64 + w * 16) * 9 + lane * 4) = v;
        }
    };

    // ---- software-pipelined tile loop: prefetch 1 tile ahead, ping-pong regs
    float sA[8], sB[8];
    loadT(sA, 0);
    for (int tt = 0; tt < TPB; tt += 2) {
        loadT(sB, tt + 1);
        tileCompute(sA, tt);
        if (tt + 2 < TPB) loadT(sA, tt + 2);
        tileCompute(sB, tt + 1);
    }
}

extern "C" void kernel_launch(void* const* d_in, const int* in_sizes, int n_in,
                              void* d_out, int out_size, void* d_ws, size_t ws_size,
                              hipStream_t stream) {
    const float* spatial = (const float*)d_in[0];
    // d_in[1] = car_stats: unused by the model, never read.
    const float* Wmx  = (const float*)d_in[2];
    const float* bmx  = (const float*)d_in[3];
    const float* Wnx  = (const float*)d_in[4];
    const float* bnx  = (const float*)d_in[5];
    const float* Wmy  = (const float*)d_in[6];
    const float* bmy  = (const float*)d_in[7];
    const float* Wny  = (const float*)d_in[8];
    const float* bny  = (const float*)d_in[9];
    const float* Wmz  = (const float*)d_in[10];
    const float* bmz  = (const float*)d_in[11];
    const float* Wnz  = (const float*)d_in[12];
    const float* bnz  = (const float*)d_in[13];
    const float* Wlin = (const float*)d_in[14];
    const float* blin = (const float*)d_in[15];
    const float* Wout = (const float*)d_in[16];
    const float* bout = (const float*)d_in[17];
    float* out = (float*)d_out;

    _Float16* frag = (_Float16*)d_ws;   // 21504 B

    prep_frags<<<dim3(42), dim3(256), 0, stream>>>(
        Wmx, bmx, Wnx, bnx, Wmy, bmy, Wny, bny, Wmz, bmz, Wnz, bnz,
        Wlin, blin, Wout, bout, frag);

    const int nb = in_sizes[0] / 27;           // 1048576, multiple of 64*TPB
    dim3 grid(nb / (64 * TPB));                // 2048 blocks, 4 waves each
    actor_mfma<<<grid, dim3(256), 0, stream>>>(spatial, frag, out);
}

// Round 4
// 241.164 us; speedup vs baseline: 1.5504x; 1.5504x over previous
//
#include <hip/hip_runtime.h>

// CombinedActorModel R10: LDS-resident weight fragments + immediate-offset
// ds_read_b128, higher occupancy.
// R8/R9 post-mortem: the allocator refuses to keep the 84-VGPR fragment array
// resident (default budget 76 -> per-tile global reloads; launch_bounds(256,4)
// -> 64 VGPR + 468 MB scratch spill, 209 us). So: fragments live in LDS,
// staged once per block; each tile/actor reads 7 frags via ds_read_b128 at
// literal offsets from a pinned 32-bit index (no addr VALU, no LICM re-hoist,
// max 28 VGPRs of frag data live at once). TPB=4 / grid 4096 for occupancy
// (23.8 KB LDS -> 6 blocks/CU = 24 waves/CU resident).
// Bias folding, per-lane ping-pong spatial loads, LDS-compacted coalesced
// stores unchanged from R7/R8 (numerically verified, absmax 1.95e-3).

typedef _Float16 half8  __attribute__((ext_vector_type(8)));
typedef float    floatx4 __attribute__((ext_vector_type(4)));

#define NFRAG 21                    // 3 actors * (4 stage1 + 2 stage2 + 1 stage3)
#define FRAG_HALFS (NFRAG * 512)    // 10752 halfs = 21504 B
#define TPB 4                       // 64-elem tiles per block

__global__ __launch_bounds__(256) void prep_frags(
    const float* __restrict__ Wmx, const float* __restrict__ bmx,
    const float* __restrict__ Wnx, const float* __restrict__ bnx,
    const float* __restrict__ Wmy, const float* __restrict__ bmy,
    const float* __restrict__ Wny, const float* __restrict__ bny,
    const float* __restrict__ Wmz, const float* __restrict__ bmz,
    const float* __restrict__ Wnz, const float* __restrict__ bnz,
    const float* __restrict__ Wlin, const float* __restrict__ blin,
    const float* __restrict__ Wout, const float* __restrict__ bout,
    _Float16* __restrict__ frag)
{
    int i = threadIdx.x + blockIdx.x * blockDim.x;
    if (i >= FRAG_HALFS) return;
    int f = i >> 9, rem = i & 511;
    int lane = rem >> 3, j = rem & 7;
    int q = lane >> 4, m = lane & 15;
    int a = f / 7, idx = f % 7;
    float v = 0.f;
    if (idx < 4) {
        // stage1 A-frag: rows = stage1 cols c, k = feature (standard 8q+j);
        // bias folded at k==27 (B operand supplies 1.0 there).
        int c = m + ((idx & 1) ? 16 : 0);
        int k = 8 * q + j;
        bool npart = (idx >= 2);
        if (c < 10) {
            if (!npart) { if (k < 6)             v = Wmx[(a*10 + c)*6 + k];
                          else if (k == 27)      v = bmx[a*10 + c]; }
            else        { if (k >= 6 && k < 9)   v = Wnx[(a*10 + c)*3 + (k-6)];
                          else if (k == 27)      v = bnx[a*10 + c]; }
        } else if (c < 20) {
            if (!npart) { if (k >= 9 && k < 15)  v = Wmy[(a*10 + c-10)*6 + (k-9)];
                          else if (k == 27)      v = bmy[a*10 + c-10]; }
            else        { if (k >= 15 && k < 18) v = Wny[(a*10 + c-10)*3 + (k-15)];
                          else if (k == 27)      v = bny[a*10 + c-10]; }
        } else if (c < 25) {
            if (!npart) { if (k >= 18 && k < 24) v = Wmz[(a*5 + c-20)*6 + (k-18)];
                          else if (k == 27)      v = bmz[a*5 + c-20]; }
            else        { if (k >= 24 && k < 27) v = Wnz[(a*5 + c-20)*3 + (k-24)];
                          else if (k == 27)      v = bnz[a*5 + c-20]; }
        }
    } else if (idx < 6) {
        // stage2 A-frag: rows = o, k permuted by sigma; bias at kc==25
        int o  = m + ((idx == 5) ? 16 : 0);
        int kc = 16 * (j >> 2) + 4 * q + (j & 3);   // sigma(q,j)
        if (o < 25) {
            if (kc < 25)       v = Wlin[(a*25 + o)*25 + kc];
            else if (kc == 25) v = blin[a*25 + o];
        }
    } else {
        // stage3 A-frag: rows = ch, k permuted by sigma; bias at ko==25
        int ko = 16 * (j >> 2) + 4 * q + (j & 3);
        if (m < 10) {
            if (ko < 25)       v = Wout[(a*15 + m)*25 + ko];
            else if (ko == 25) v = bout[a*15 + m];
        }
    }
    frag[(size_t)f * 512 + lane * 8 + j] = (_Float16)v;
}

__global__ __launch_bounds__(256) void actor_mfma(
    const float* __restrict__ spatial,
    const _Float16* __restrict__ frag,
    float* __restrict__ out)
{
    __shared__ _Float16 lds_f[FRAG_HALFS];   // 21504 B, block-shared constants
    __shared__ float    lds_o[4 * 144];      // per-wave output compaction

    const int t = threadIdx.x;
    const int lane = t & 63, w = t >> 6;
    const int q = lane >> 4, e = lane & 15;
    const size_t b0 = (size_t)blockIdx.x * (64 * TPB);

    // ---- cooperative frag staging: 1344 float4, once per block
    {
        const float4* gf = (const float4*)frag;
        float4* df = (float4*)lds_f;
        #pragma unroll
        for (int k = 0; k < 6; ++k) {
            int idx = t + k * 256;
            if (idx < 1344) df[idx] = gf[idx];
        }
    }

    // ---- per-lane constants for the spatial gather (invariant across tiles)
    const float* sbase = spatial + (b0 + (size_t)(w * 16 + e)) * 27 + 8 * q;
    float vbase[8];
    #pragma unroll
    for (int j = 0; j < 8; ++j) vbase[j] = ((8 * q + j) == 27) ? 1.f : 0.f;

    float* const ldso = lds_o + w * 144;
    const floatx4 z = {0.f, 0.f, 0.f, 0.f};

    __syncthreads();

    // 32-bit LDS half8-index; opaquely re-pinned per actor so the 21
    // loop-invariant ds_reads can't be hoisted into (and spill) registers.
    int fo = lane;

    auto loadT = [&](float (&dst)[8], int tt) {
        const float* s_ = sbase + (size_t)tt * (64 * 27);
        #pragma unroll
        for (int j = 0; j < 8; ++j) {
            int k = 8 * q + j;
            dst[j] = (k < 27) ? s_[j] : vbase[j];
        }
    };

    auto tileCompute = [&](const float (&cur)[8], int tt) {
        half8 Bs;
        #pragma unroll
        for (int j = 0; j < 8; ++j) Bs[j] = (_Float16)cur[j];

        floatx4 oacc[3];
        #pragma unroll
        for (int a = 0; a < 3; ++a) {
            asm volatile("" : "+v"(fo));   // opaque: blocks LICM/clustering
            const half8* fp = (const half8*)lds_f + fo;
            const int fb = a * 7;
            // stage1: D[c][e]; ds_read_b128 at literal offsets feeds MFMA
            half8 P;
            {
                floatx4 M0 = __builtin_amdgcn_mfma_f32_16x16x32_f16(fp[(fb+0)*64], Bs, z, 0,0,0);
                floatx4 N0 = __builtin_amdgcn_mfma_f32_16x16x32_f16(fp[(fb+2)*64], Bs, z, 0,0,0);
                #pragma unroll
                for (int r = 0; r < 4; ++r) P[r] = (_Float16)(M0[r] * N0[r]);
            }
            {
                floatx4 M1 = __builtin_amdgcn_mfma_f32_16x16x32_f16(fp[(fb+1)*64], Bs, z, 0,0,0);
                floatx4 N1 = __builtin_amdgcn_mfma_f32_16x16x32_f16(fp[(fb+3)*64], Bs, z, 0,0,0);
                #pragma unroll
                for (int r = 0; r < 4; ++r) P[4 + r] = (_Float16)(M1[r] * N1[r]);
            }
            // sigma-packed slot kc=25 (q=2,j=5) carries the stage2 bias col
            if (q == 2) P[5] = (_Float16)1.f;

            // stage2: D[o][e] (Wlin frag sigma-packed, bias at kc=25)
            floatx4 H0 = __builtin_amdgcn_mfma_f32_16x16x32_f16(fp[(fb+4)*64], P, z, 0,0,0);
            floatx4 H1 = __builtin_amdgcn_mfma_f32_16x16x32_f16(fp[(fb+5)*64], P, z, 0,0,0);

            // softsign -> sigma-packed B operand for stage3; bias column = 1.0
            half8 Hh;
            #pragma unroll
            for (int r = 0; r < 4; ++r) {
                float v0 = H0[r];
                Hh[r]     = (_Float16)(v0 * __builtin_amdgcn_rcpf(1.0f + fabsf(v0)));
                float v1 = H1[r];
                Hh[4 + r] = (_Float16)(v1 * __builtin_amdgcn_rcpf(1.0f + fabsf(v1)));
            }
            if (q == 2) Hh[5] = (_Float16)1.f;

            // stage3: D[ch][e]; lane (e,q) reg r holds ch = 4q+r (gate ch9 @ q=2,r=1)
            oacc[a] = __builtin_amdgcn_mfma_f32_16x16x32_f16(fp[(fb+6)*64], Hh, z, 0,0,0);
        }

        // ---- epilogue: softmax over actors of ch9, weighted sum of ch0..8
        const int src9 = 32 + e;   // lane (e, q=2); its reg1 = ch9
        float g0 = __shfl(oacc[0][1], src9, 64);
        float g1 = __shfl(oacc[1][1], src9, 64);
        float g2 = __shfl(oacc[2][1], src9, 64);
        float mx = fmaxf(g0, fmaxf(g1, g2));
        float e0 = __expf(g0 - mx);
        float e1 = __expf(g1 - mx);
        float e2 = __expf(g2 - mx);
        float inv = __builtin_amdgcn_rcpf(e0 + e1 + e2);
        e0 *= inv; e1 *= inv; e2 *= inv;

        float res[4];
        #pragma unroll
        for (int r = 0; r < 4; ++r)
            res[r] = oacc[0][r] * e0 + oacc[1][r] * e1 + oacc[2][r] * e2;

        // ---- compact to this wave's scratch, coalesced float4 store
        if (q < 2) {
            #pragma unroll
            for (int r = 0; r < 4; ++r) ldso[e * 9 + 4 * q + r] = res[r];
        } else if (q == 2) {
            ldso[e * 9 + 8] = res[0];
        }
        // same-wave DS ordering: writes retire before the reads below issue
        if (lane < 36) {
            float4 v = *(const float4*)(ldso + lane * 4);
            *(float4*)(out + (b0 + (size_t)tt * 64 + w * 16) * 9 + lane * 4) = v;
        }
    };

    // ---- software-pipelined tile loop: prefetch 1 tile ahead, ping-pong regs
    float sA[8], sB[8];
    loadT(sA, 0);
    for (int tt = 0; tt < TPB; tt += 2) {
        loadT(sB, tt + 1);
        tileCompute(sA, tt);
        if (tt + 2 < TPB) loadT(sA, tt + 2);
        tileCompute(sB, tt + 1);
    }
}

extern "C" void kernel_launch(void* const* d_in, const int* in_sizes, int n_in,
                              void* d_out, int out_size, void* d_ws, size_t ws_size,
                              hipStream_t stream) {
    const float* spatial = (const float*)d_in[0];
    // d_in[1] = car_stats: unused by the model, never read.
    const float* Wmx  = (const float*)d_in[2];
    const float* bmx  = (const float*)d_in[3];
    const float* Wnx  = (const float*)d_in[4];
    const float* bnx  = (const float*)d_in[5];
    const float* Wmy  = (const float*)d_in[6];
    const float* bmy  = (const float*)d_in[7];
    const float* Wny  = (const float*)d_in[8];
    const float* bny  = (const float*)d_in[9];
    const float* Wmz  = (const float*)d_in[10];
    const float* bmz  = (const float*)d_in[11];
    const float* Wnz  = (const float*)d_in[12];
    const float* bnz  = (const float*)d_in[13];
    const float* Wlin = (const float*)d_in[14];
    const float* blin = (const float*)d_in[15];
    const float* Wout = (const float*)d_in[16];
    const float* bout = (const float*)d_in[17];
    float* out = (float*)d_out;

    _Float16* frag = (_Float16*)d_ws;   // 21504 B

    prep_frags<<<dim3(42), dim3(256), 0, stream>>>(
        Wmx, bmx, Wnx, bnx, Wmy, bmy, Wny, bny, Wmz, bmz, Wnz, bnz,
        Wlin, blin, Wout, bout, frag);

    const int nb = in_sizes[0] / 27;           // 1048576, multiple of 64*TPB
    dim3 grid(nb / (64 * TPB));                // 4096 blocks, 4 waves each
    actor_mfma<<<grid, dim3(256), 0, stream>>>(spatial, frag, out);
}

// Round 5
// 233.066 us; speedup vs baseline: 1.6043x; 1.0347x over previous
//
#include <hip/hip_runtime.h>

// CombinedActorModel R11: R10 + 512-thread blocks for occupancy.
// R10 post-mortem: spill fixed (VGPR 40, clean FETCH/WRITE), dur 85us, but
// VALUBusy 47% / occupancy 55% -> issue-gap-bound. VGPR=40 fits the 8-wave/SIMD
// bin; the limiter was 4-wave blocks x 24KB LDS. 512-thread blocks amortize the
// same 21.5KB frag image over 8 waves: 4 blocks/CU x 8 waves = 32 waves/CU
// (100% cap), and halve the per-block frag staging traffic. Everything else
// (LDS frags + literal-offset ds_read from pinned index, bias folding into
// spare K-slots, ping-pong spatial prefetch, LDS-compacted stores) unchanged.

typedef _Float16 half8  __attribute__((ext_vector_type(8)));
typedef float    floatx4 __attribute__((ext_vector_type(4)));

#define NFRAG 21                    // 3 actors * (4 stage1 + 2 stage2 + 1 stage3)
#define FRAG_HALFS (NFRAG * 512)    // 10752 halfs = 21504 B
#define TPB 4                       // tiles per block (tile = 128 elements)
#define NWAVES 8                    // 512-thread blocks

__global__ __launch_bounds__(256) void prep_frags(
    const float* __restrict__ Wmx, const float* __restrict__ bmx,
    const float* __restrict__ Wnx, const float* __restrict__ bnx,
    const float* __restrict__ Wmy, const float* __restrict__ bmy,
    const float* __restrict__ Wny, const float* __restrict__ bny,
    const float* __restrict__ Wmz, const float* __restrict__ bmz,
    const float* __restrict__ Wnz, const float* __restrict__ bnz,
    const float* __restrict__ Wlin, const float* __restrict__ blin,
    const float* __restrict__ Wout, const float* __restrict__ bout,
    _Float16* __restrict__ frag)
{
    int i = threadIdx.x + blockIdx.x * blockDim.x;
    if (i >= FRAG_HALFS) return;
    int f = i >> 9, rem = i & 511;
    int lane = rem >> 3, j = rem & 7;
    int q = lane >> 4, m = lane & 15;
    int a = f / 7, idx = f % 7;
    float v = 0.f;
    if (idx < 4) {
        int c = m + ((idx & 1) ? 16 : 0);
        int k = 8 * q + j;
        bool npart = (idx >= 2);
        if (c < 10) {
            if (!npart) { if (k < 6)             v = Wmx[(a*10 + c)*6 + k];
                          else if (k == 27)      v = bmx[a*10 + c]; }
            else        { if (k >= 6 && k < 9)   v = Wnx[(a*10 + c)*3 + (k-6)];
                          else if (k == 27)      v = bnx[a*10 + c]; }
        } else if (c < 20) {
            if (!npart) { if (k >= 9 && k < 15)  v = Wmy[(a*10 + c-10)*6 + (k-9)];
                          else if (k == 27)      v = bmy[a*10 + c-10]; }
            else        { if (k >= 15 && k < 18) v = Wny[(a*10 + c-10)*3 + (k-15)];
                          else if (k == 27)      v = bny[a*10 + c-10]; }
        } else if (c < 25) {
            if (!npart) { if (k >= 18 && k < 24) v = Wmz[(a*5 + c-20)*6 + (k-18)];
                          else if (k == 27)      v = bmz[a*5 + c-20]; }
            else        { if (k >= 24 && k < 27) v = Wnz[(a*5 + c-20)*3 + (k-24)];
                          else if (k == 27)      v = bnz[a*5 + c-20]; }
        }
    } else if (idx < 6) {
        int o  = m + ((idx == 5) ? 16 : 0);
        int kc = 16 * (j >> 2) + 4 * q + (j & 3);   // sigma(q,j)
        if (o < 25) {
            if (kc < 25)       v = Wlin[(a*25 + o)*25 + kc];
            else if (kc == 25) v = blin[a*25 + o];
        }
    } else {
        int ko = 16 * (j >> 2) + 4 * q + (j & 3);
        if (m < 10) {
            if (ko < 25)       v = Wout[(a*15 + m)*25 + ko];
            else if (ko == 25) v = bout[a*15 + m];
        }
    }
    frag[(size_t)f * 512 + lane * 8 + j] = (_Float16)v;
}

__global__ __launch_bounds__(512) void actor_mfma(
    const float* __restrict__ spatial,
    const _Float16* __restrict__ frag,
    float* __restrict__ out)
{
    __shared__ _Float16 lds_f[FRAG_HALFS];     // 21504 B, block-shared constants
    __shared__ float    lds_o[NWAVES * 144];   // per-wave output compaction

    const int t = threadIdx.x;
    const int lane = t & 63, w = t >> 6;
    const int q = lane >> 4, e = lane & 15;
    const size_t b0 = (size_t)blockIdx.x * (16 * NWAVES * TPB);

    // ---- cooperative frag staging: 1344 float4, once per block
    {
        const float4* gf = (const float4*)frag;
        float4* df = (float4*)lds_f;
        #pragma unroll
        for (int k = 0; k < 3; ++k) {
            int idx = t + k * 512;
            if (idx < 1344) df[idx] = gf[idx];
        }
    }

    // ---- per-lane constants for the spatial gather (invariant across tiles)
    const float* sbase = spatial + (b0 + (size_t)(w * 16 + e)) * 27 + 8 * q;
    float vbase[8];
    #pragma unroll
    for (int j = 0; j < 8; ++j) vbase[j] = ((8 * q + j) == 27) ? 1.f : 0.f;

    float* const ldso = lds_o + w * 144;
    const floatx4 z = {0.f, 0.f, 0.f, 0.f};

    __syncthreads();

    // 32-bit LDS half8-index; opaquely re-pinned per actor so the 21
    // loop-invariant ds_reads can't be hoisted into (and spill) registers.
    int fo = lane;

    auto loadT = [&](float (&dst)[8], int tt) {
        const float* s_ = sbase + (size_t)tt * (16 * NWAVES * 27);
        #pragma unroll
        for (int j = 0; j < 8; ++j) {
            int k = 8 * q + j;
            dst[j] = (k < 27) ? s_[j] : vbase[j];
        }
    };

    auto tileCompute = [&](const float (&cur)[8], int tt) {
        half8 Bs;
        #pragma unroll
        for (int j = 0; j < 8; ++j) Bs[j] = (_Float16)cur[j];

        floatx4 oacc[3];
        #pragma unroll
        for (int a = 0; a < 3; ++a) {
            asm volatile("" : "+v"(fo));   // opaque: blocks LICM/clustering
            const half8* fp = (const half8*)lds_f + fo;
            const int fb = a * 7;
            // stage1: D[c][e]; ds_read_b128 at literal offsets feeds MFMA
            half8 P;
            {
                floatx4 M0 = __builtin_amdgcn_mfma_f32_16x16x32_f16(fp[(fb+0)*64], Bs, z, 0,0,0);
                floatx4 N0 = __builtin_amdgcn_mfma_f32_16x16x32_f16(fp[(fb+2)*64], Bs, z, 0,0,0);
                #pragma unroll
                for (int r = 0; r < 4; ++r) P[r] = (_Float16)(M0[r] * N0[r]);
            }
            {
                floatx4 M1 = __builtin_amdgcn_mfma_f32_16x16x32_f16(fp[(fb+1)*64], Bs, z, 0,0,0);
                floatx4 N1 = __builtin_amdgcn_mfma_f32_16x16x32_f16(fp[(fb+3)*64], Bs, z, 0,0,0);
                #pragma unroll
                for (int r = 0; r < 4; ++r) P[4 + r] = (_Float16)(M1[r] * N1[r]);
            }
            // sigma-packed slot kc=25 (q=2,j=5) carries the stage2 bias col
            if (q == 2) P[5] = (_Float16)1.f;

            // stage2: D[o][e] (Wlin frag sigma-packed, bias at kc=25)
            floatx4 H0 = __builtin_amdgcn_mfma_f32_16x16x32_f16(fp[(fb+4)*64], P, z, 0,0,0);
            floatx4 H1 = __builtin_amdgcn_mfma_f32_16x16x32_f16(fp[(fb+5)*64], P, z, 0,0,0);

            // softsign -> sigma-packed B operand for stage3; bias column = 1.0
            half8 Hh;
            #pragma unroll
            for (int r = 0; r < 4; ++r) {
                float v0 = H0[r];
                Hh[r]     = (_Float16)(v0 * __builtin_amdgcn_rcpf(1.0f + fabsf(v0)));
                float v1 = H1[r];
                Hh[4 + r] = (_Float16)(v1 * __builtin_amdgcn_rcpf(1.0f + fabsf(v1)));
            }
            if (q == 2) Hh[5] = (_Float16)1.f;

            // stage3: D[ch][e]; lane (e,q) reg r holds ch = 4q+r (gate ch9 @ q=2,r=1)
            oacc[a] = __builtin_amdgcn_mfma_f32_16x16x32_f16(fp[(fb+6)*64], Hh, z, 0,0,0);
        }

        // ---- epilogue: softmax over actors of ch9, weighted sum of ch0..8
        const int src9 = 32 + e;   // lane (e, q=2); its reg1 = ch9
        float g0 = __shfl(oacc[0][1], src9, 64);
        float g1 = __shfl(oacc[1][1], src9, 64);
        float g2 = __shfl(oacc[2][1], src9, 64);
        float mx = fmaxf(g0, fmaxf(g1, g2));
        float e0 = __expf(g0 - mx);
        float e1 = __expf(g1 - mx);
        float e2 = __expf(g2 - mx);
        float inv = __builtin_amdgcn_rcpf(e0 + e1 + e2);
        e0 *= inv; e1 *= inv; e2 *= inv;

        float res[4];
        #pragma unroll
        for (int r = 0; r < 4; ++r)
            res[r] = oacc[0][r] * e0 + oacc[1][r] * e1 + oacc[2][r] * e2;

        // ---- compact to this wave's scratch, coalesced float4 store
        if (q < 2) {
            #pragma unroll
            for (int r = 0; r < 4; ++r) ldso[e * 9 + 4 * q + r] = res[r];
        } else if (q == 2) {
            ldso[e * 9 + 8] = res[0];
        }
        // same-wave DS ordering: writes retire before the reads below issue
        if (lane < 36) {
            float4 v = *(const float4*)(ldso + lane * 4);
            *(float4*)(out + (b0 + (size_t)tt * (16 * NWAVES) + w * 16) * 9 + lane * 4) = v;
        }
    };

    // ---- software-pipelined tile loop: prefetch 1 tile ahead, ping-pong regs
    float sA[8], sB[8];
    loadT(sA, 0);
    for (int tt = 0; tt < TPB; tt += 2) {
        loadT(sB, tt + 1);
        tileCompute(sA, tt);
        if (tt + 2 < TPB) loadT(sA, tt + 2);
        tileCompute(sB, tt + 1);
    }
}

extern "C" void kernel_launch(void* const* d_in, const int* in_sizes, int n_in,
                              void* d_out, int out_size, void* d_ws, size_t ws_size,
                              hipStream_t stream) {
    const float* spatial = (const float*)d_in[0];
    // d_in[1] = car_stats: unused by the model, never read.
    const float* Wmx  = (const float*)d_in[2];
    const float* bmx  = (const float*)d_in[3];
    const float* Wnx  = (const float*)d_in[4];
    const float* bnx  = (const float*)d_in[5];
    const float* Wmy  = (const float*)d_in[6];
    const float* bmy  = (const float*)d_in[7];
    const float* Wny  = (const float*)d_in[8];
    const float* bny  = (const float*)d_in[9];
    const float* Wmz  = (const float*)d_in[10];
    const float* bmz  = (const float*)d_in[11];
    const float* Wnz  = (const float*)d_in[12];
    const float* bnz  = (const float*)d_in[13];
    const float* Wlin = (const float*)d_in[14];
    const float* blin = (const float*)d_in[15];
    const float* Wout = (const float*)d_in[16];
    const float* bout = (const float*)d_in[17];
    float* out = (float*)d_out;

    _Float16* frag = (_Float16*)d_ws;   // 21504 B

    prep_frags<<<dim3(42), dim3(256), 0, stream>>>(
        Wmx, bmx, Wnx, bnx, Wmy, bmy, Wny, bny, Wmz, bmz, Wnz, bnz,
        Wlin, blin, Wout, bout, frag);

    const int nb = in_sizes[0] / 27;           // 1048576, multiple of 16*NWAVES*TPB
    dim3 grid(nb / (16 * NWAVES * TPB));       // 2048 blocks, 8 waves each
    actor_mfma<<<grid, dim3(64 * NWAVES), 0, stream>>>(spatial, frag, out);
}

// Round 8
// 223.638 us; speedup vs baseline: 1.6719x; 1.0422x over previous
//
#include <hip/hip_runtime.h>

// CombinedActorModel R12b: R11 + packed f32->f16 conversion (v_cvt_pkrtz).
// (R12 failed to compile: cvt_pkrtz returns an __fp16 ext-vector, not
// _Float16 -- union pair-slots retyped to __fp16, bit-identical layout.)
// R11 post-mortem: 67us, VALUBusy 47%, occupancy 63%, VGPR 32, HBM 17% --
// compute/latency bound. Largest reducible VALU block: every stage boundary
// (Bs, P, Hh) did 8 scalar v_cvt_f16_f32 + pack ops. cvt_pkrtz converts a
// pair straight into the packed register: 3x(12-20 ops) -> 3x(4-8 ops) per
// actor per tile. Bias-slot overrides (q==2 -> 1.0) folded into the f32
// value before packing (cndmask) instead of f16 sub-register inserts.
// Everything else (LDS frags + literal-offset ds_read from pinned index,
// bias folding, ping-pong spatial prefetch, 512-thread blocks, TPB=4,
// LDS-compacted stores) unchanged from R11.

typedef _Float16 half8   __attribute__((ext_vector_type(8)));
typedef __fp16   fp16x2  __attribute__((ext_vector_type(2)));
typedef float    floatx4 __attribute__((ext_vector_type(4)));

#define NFRAG 21                    // 3 actors * (4 stage1 + 2 stage2 + 1 stage3)
#define FRAG_HALFS (NFRAG * 512)    // 10752 halfs = 21504 B
#define TPB 4                       // tiles per block (tile = 128 elements)
#define NWAVES 8                    // 512-thread blocks

__global__ __launch_bounds__(256) void prep_frags(
    const float* __restrict__ Wmx, const float* __restrict__ bmx,
    const float* __restrict__ Wnx, const float* __restrict__ bnx,
    const float* __restrict__ Wmy, const float* __restrict__ bmy,
    const float* __restrict__ Wny, const float* __restrict__ bny,
    const float* __restrict__ Wmz, const float* __restrict__ bmz,
    const float* __restrict__ Wnz, const float* __restrict__ bnz,
    const float* __restrict__ Wlin, const float* __restrict__ blin,
    const float* __restrict__ Wout, const float* __restrict__ bout,
    _Float16* __restrict__ frag)
{
    int i = threadIdx.x + blockIdx.x * blockDim.x;
    if (i >= FRAG_HALFS) return;
    int f = i >> 9, rem = i & 511;
    int lane = rem >> 3, j = rem & 7;
    int q = lane >> 4, m = lane & 15;
    int a = f / 7, idx = f % 7;
    float v = 0.f;
    if (idx < 4) {
        int c = m + ((idx & 1) ? 16 : 0);
        int k = 8 * q + j;
        bool npart = (idx >= 2);
        if (c < 10) {
            if (!npart) { if (k < 6)             v = Wmx[(a*10 + c)*6 + k];
                          else if (k == 27)      v = bmx[a*10 + c]; }
            else        { if (k >= 6 && k < 9)   v = Wnx[(a*10 + c)*3 + (k-6)];
                          else if (k == 27)      v = bnx[a*10 + c]; }
        } else if (c < 20) {
            if (!npart) { if (k >= 9 && k < 15)  v = Wmy[(a*10 + c-10)*6 + (k-9)];
                          else if (k == 27)      v = bmy[a*10 + c-10]; }
            else        { if (k >= 15 && k < 18) v = Wny[(a*10 + c-10)*3 + (k-15)];
                          else if (k == 27)      v = bny[a*10 + c-10]; }
        } else if (c < 25) {
            if (!npart) { if (k >= 18 && k < 24) v = Wmz[(a*5 + c-20)*6 + (k-18)];
                          else if (k == 27)      v = bmz[a*5 + c-20]; }
            else        { if (k >= 24 && k < 27) v = Wnz[(a*5 + c-20)*3 + (k-24)];
                          else if (k == 27)      v = bnz[a*5 + c-20]; }
        }
    } else if (idx < 6) {
        int o  = m + ((idx == 5) ? 16 : 0);
        int kc = 16 * (j >> 2) + 4 * q + (j & 3);   // sigma(q,j)
        if (o < 25) {
            if (kc < 25)       v = Wlin[(a*25 + o)*25 + kc];
            else if (kc == 25) v = blin[a*25 + o];
        }
    } else {
        int ko = 16 * (j >> 2) + 4 * q + (j & 3);
        if (m < 10) {
            if (ko < 25)       v = Wout[(a*15 + m)*25 + ko];
            else if (ko == 25) v = bout[a*15 + m];
        }
    }
    frag[(size_t)f * 512 + lane * 8 + j] = (_Float16)v;
}

__global__ __launch_bounds__(512) void actor_mfma(
    const float* __restrict__ spatial,
    const _Float16* __restrict__ frag,
    float* __restrict__ out)
{
    __shared__ _Float16 lds_f[FRAG_HALFS];     // 21504 B, block-shared constants
    __shared__ float    lds_o[NWAVES * 144];   // per-wave output compaction

    const int t = threadIdx.x;
    const int lane = t & 63, w = t >> 6;
    const int q = lane >> 4, e = lane & 15;
    const size_t b0 = (size_t)blockIdx.x * (16 * NWAVES * TPB);

    // ---- cooperative frag staging: 1344 float4, once per block
    {
        const float4* gf = (const float4*)frag;
        float4* df = (float4*)lds_f;
        #pragma unroll
        for (int k = 0; k < 3; ++k) {
            int idx = t + k * 512;
            if (idx < 1344) df[idx] = gf[idx];
        }
    }

    // ---- per-lane constants for the spatial gather (invariant across tiles)
    const float* sbase = spatial + (b0 + (size_t)(w * 16 + e)) * 27 + 8 * q;
    float vbase[8];
    #pragma unroll
    for (int j = 0; j < 8; ++j) vbase[j] = ((8 * q + j) == 27) ? 1.f : 0.f;

    float* const ldso = lds_o + w * 144;
    const floatx4 z = {0.f, 0.f, 0.f, 0.f};

    __syncthreads();

    // 32-bit LDS half8-index; opaquely re-pinned per actor so the 21
    // loop-invariant ds_reads can't be hoisted into (and spill) registers.
    int fo = lane;

    auto loadT = [&](float (&dst)[8], int tt) {
        const float* s_ = sbase + (size_t)tt * (16 * NWAVES * 27);
        #pragma unroll
        for (int j = 0; j < 8; ++j) {
            int k = 8 * q + j;
            dst[j] = (k < 27) ? s_[j] : vbase[j];
        }
    };

    auto tileCompute = [&](const float (&cur)[8], int tt) {
        union H8u { half8 v; fp16x2 p[4]; };

        H8u Bs;
        #pragma unroll
        for (int p_ = 0; p_ < 4; ++p_)
            Bs.p[p_] = __builtin_amdgcn_cvt_pkrtz(cur[2*p_], cur[2*p_+1]);

        floatx4 oacc[3];
        #pragma unroll
        for (int a = 0; a < 3; ++a) {
            asm volatile("" : "+v"(fo));   // opaque: blocks LICM/clustering
            const half8* fp = (const half8*)lds_f + fo;
            const int fb = a * 7;
            // stage1: D[c][e]; ds_read_b128 at literal offsets feeds MFMA
            H8u P;
            {
                floatx4 M0 = __builtin_amdgcn_mfma_f32_16x16x32_f16(fp[(fb+0)*64], Bs.v, z, 0,0,0);
                floatx4 N0 = __builtin_amdgcn_mfma_f32_16x16x32_f16(fp[(fb+2)*64], Bs.v, z, 0,0,0);
                P.p[0] = __builtin_amdgcn_cvt_pkrtz(M0[0]*N0[0], M0[1]*N0[1]);
                P.p[1] = __builtin_amdgcn_cvt_pkrtz(M0[2]*N0[2], M0[3]*N0[3]);
            }
            {
                floatx4 M1 = __builtin_amdgcn_mfma_f32_16x16x32_f16(fp[(fb+1)*64], Bs.v, z, 0,0,0);
                floatx4 N1 = __builtin_amdgcn_mfma_f32_16x16x32_f16(fp[(fb+3)*64], Bs.v, z, 0,0,0);
                // sigma-packed slot kc=25 (q=2, elem 5) carries the stage2 bias
                float g5 = (q == 2) ? 1.f : M1[1]*N1[1];
                P.p[2] = __builtin_amdgcn_cvt_pkrtz(M1[0]*N1[0], g5);
                P.p[3] = __builtin_amdgcn_cvt_pkrtz(M1[2]*N1[2], M1[3]*N1[3]);
            }

            // stage2: D[o][e] (Wlin frag sigma-packed, bias at kc=25)
            floatx4 H0 = __builtin_amdgcn_mfma_f32_16x16x32_f16(fp[(fb+4)*64], P.v, z, 0,0,0);
            floatx4 H1 = __builtin_amdgcn_mfma_f32_16x16x32_f16(fp[(fb+5)*64], P.v, z, 0,0,0);

            // softsign -> packed B operand for stage3; bias column = 1.0
            auto ss = [](float v_) {
                return v_ * __builtin_amdgcn_rcpf(1.0f + __builtin_fabsf(v_));
            };
            H8u Hh;
            Hh.p[0] = __builtin_amdgcn_cvt_pkrtz(ss(H0[0]), ss(H0[1]));
            Hh.p[1] = __builtin_amdgcn_cvt_pkrtz(ss(H0[2]), ss(H0[3]));
            float h5 = (q == 2) ? 1.f : ss(H1[1]);
            Hh.p[2] = __builtin_amdgcn_cvt_pkrtz(ss(H1[0]), h5);
            Hh.p[3] = __builtin_amdgcn_cvt_pkrtz(ss(H1[2]), ss(H1[3]));

            // stage3: D[ch][e]; lane (e,q) reg r holds ch = 4q+r (gate ch9 @ q=2,r=1)
            oacc[a] = __builtin_amdgcn_mfma_f32_16x16x32_f16(fp[(fb+6)*64], Hh.v, z, 0,0,0);
        }

        // ---- epilogue: softmax over actors of ch9, weighted sum of ch0..8
        const int src9 = 32 + e;   // lane (e, q=2); its reg1 = ch9
        float g0 = __shfl(oacc[0][1], src9, 64);
        float g1 = __shfl(oacc[1][1], src9, 64);
        float g2 = __shfl(oacc[2][1], src9, 64);
        float mx = fmaxf(g0, fmaxf(g1, g2));
        float e0 = __expf(g0 - mx);
        float e1 = __expf(g1 - mx);
        float e2 = __expf(g2 - mx);
        float inv = __builtin_amdgcn_rcpf(e0 + e1 + e2);
        e0 *= inv; e1 *= inv; e2 *= inv;

        float res[4];
        #pragma unroll
        for (int r = 0; r < 4; ++r)
            res[r] = oacc[0][r] * e0 + oacc[1][r] * e1 + oacc[2][r] * e2;

        // ---- compact to this wave's scratch, coalesced float4 store
        if (q < 2) {
            #pragma unroll
            for (int r = 0; r < 4; ++r) ldso[e * 9 + 4 * q + r] = res[r];
        } else if (q == 2) {
            ldso[e * 9 + 8] = res[0];
        }
        // same-wave DS ordering: writes retire before the reads below issue
        if (lane < 36) {
            float4 v = *(const float4*)(ldso + lane * 4);
            *(float4*)(out + (b0 + (size_t)tt * (16 * NWAVES) + w * 16) * 9 + lane * 4) = v;
        }
    };

    // ---- software-pipelined tile loop: prefetch 1 tile ahead, ping-pong regs
    float sA[8], sB[8];
    loadT(sA, 0);
    for (int tt = 0; tt < TPB; tt += 2) {
        loadT(sB, tt + 1);
        tileCompute(sA, tt);
        if (tt + 2 < TPB) loadT(sA, tt + 2);
        tileCompute(sB, tt + 1);
    }
}

extern "C" void kernel_launch(void* const* d_in, const int* in_sizes, int n_in,
                              void* d_out, int out_size, void* d_ws, size_t ws_size,
                              hipStream_t stream) {
    const float* spatial = (const float*)d_in[0];
    // d_in[1] = car_stats: unused by the model, never read.
    const float* Wmx  = (const float*)d_in[2];
    const float* bmx  = (const float*)d_in[3];
    const float* Wnx  = (const float*)d_in[4];
    const float* bnx  = (const float*)d_in[5];
    const float* Wmy  = (const float*)d_in[6];
    const float* bmy  = (const float*)d_in[7];
    const float* Wny  = (const float*)d_in[8];
    const float* bny  = (const float*)d_in[9];
    const float* Wmz  = (const float*)d_in[10];
    const float* bmz  = (const float*)d_in[11];
    const float* Wnz  = (const float*)d_in[12];
    const float* bnz  = (const float*)d_in[13];
    const float* Wlin = (const float*)d_in[14];
    const float* blin = (const float*)d_in[15];
    const float* Wout = (const float*)d_in[16];
    const float* bout = (const float*)d_in[17];
    float* out = (float*)d_out;

    _Float16* frag = (_Float16*)d_ws;   // 21504 B

    prep_frags<<<dim3(42), dim3(256), 0, stream>>>(
        Wmx, bmx, Wnx, bnx, Wmy, bmy, Wny, bny, Wmz, bmz, Wnz, bnz,
        Wlin, blin, Wout, bout, frag);

    const int nb = in_sizes[0] / 27;           // 1048576, multiple of 16*NWAVES*TPB
    dim3 grid(nb / (16 * NWAVES * TPB));       // 2048 blocks, 8 waves each
    actor_mfma<<<grid, dim3(64 * NWAVES), 0, stream>>>(spatial, frag, out);
}

// Round 9
// 223.565 us; speedup vs baseline: 1.6725x; 1.0003x over previous
//
#include <hip/hip_runtime.h>

// CombinedActorModel R13: paired-tile compute with shared fragment reads.
// R12b confirmed instruction-count cuts pay (67 -> ~58us via cvt_pkrtz).
// Remaining structure cost: every 16-elem tile re-read all 21 frags from LDS
// and ran one serial st1->st2->st3 chain per wave. Now tiles are processed in
// PAIRS per actor: one set of 7 ds_read_b128 feeds TWO independent tile
// chains (2x ILP inside a wave, half the LDS reads). oacc/Bs kept in named/
// statically-unrolled storage (rule #20). The fo pin still blocks LICM from
// hoisting all 21 frags across pairs (the R7/R8 spill disease).
// Everything else (bias folding into spare K-slots, LDS frag image,
// 512-thread blocks, TPB=4, LDS-compacted coalesced stores) unchanged.

typedef _Float16 half8   __attribute__((ext_vector_type(8)));
typedef __fp16   fp16x2  __attribute__((ext_vector_type(2)));
typedef float    floatx4 __attribute__((ext_vector_type(4)));

#define NFRAG 21                    // 3 actors * (4 stage1 + 2 stage2 + 1 stage3)
#define FRAG_HALFS (NFRAG * 512)    // 10752 halfs = 21504 B
#define TPB 4                       // tiles per block (tile = 128 elements)
#define NWAVES 8                    // 512-thread blocks

__global__ __launch_bounds__(256) void prep_frags(
    const float* __restrict__ Wmx, const float* __restrict__ bmx,
    const float* __restrict__ Wnx, const float* __restrict__ bnx,
    const float* __restrict__ Wmy, const float* __restrict__ bmy,
    const float* __restrict__ Wny, const float* __restrict__ bny,
    const float* __restrict__ Wmz, const float* __restrict__ bmz,
    const float* __restrict__ Wnz, const float* __restrict__ bnz,
    const float* __restrict__ Wlin, const float* __restrict__ blin,
    const float* __restrict__ Wout, const float* __restrict__ bout,
    _Float16* __restrict__ frag)
{
    int i = threadIdx.x + blockIdx.x * blockDim.x;
    if (i >= FRAG_HALFS) return;
    int f = i >> 9, rem = i & 511;
    int lane = rem >> 3, j = rem & 7;
    int q = lane >> 4, m = lane & 15;
    int a = f / 7, idx = f % 7;
    float v = 0.f;
    if (idx < 4) {
        int c = m + ((idx & 1) ? 16 : 0);
        int k = 8 * q + j;
        bool npart = (idx >= 2);
        if (c < 10) {
            if (!npart) { if (k < 6)             v = Wmx[(a*10 + c)*6 + k];
                          else if (k == 27)      v = bmx[a*10 + c]; }
            else        { if (k >= 6 && k < 9)   v = Wnx[(a*10 + c)*3 + (k-6)];
                          else if (k == 27)      v = bnx[a*10 + c]; }
        } else if (c < 20) {
            if (!npart) { if (k >= 9 && k < 15)  v = Wmy[(a*10 + c-10)*6 + (k-9)];
                          else if (k == 27)      v = bmy[a*10 + c-10]; }
            else        { if (k >= 15 && k < 18) v = Wny[(a*10 + c-10)*3 + (k-15)];
                          else if (k == 27)      v = bny[a*10 + c-10]; }
        } else if (c < 25) {
            if (!npart) { if (k >= 18 && k < 24) v = Wmz[(a*5 + c-20)*6 + (k-18)];
                          else if (k == 27)      v = bmz[a*5 + c-20]; }
            else        { if (k >= 24 && k < 27) v = Wnz[(a*5 + c-20)*3 + (k-24)];
                          else if (k == 27)      v = bnz[a*5 + c-20]; }
        }
    } else if (idx < 6) {
        int o  = m + ((idx == 5) ? 16 : 0);
        int kc = 16 * (j >> 2) + 4 * q + (j & 3);   // sigma(q,j)
        if (o < 25) {
            if (kc < 25)       v = Wlin[(a*25 + o)*25 + kc];
            else if (kc == 25) v = blin[a*25 + o];
        }
    } else {
        int ko = 16 * (j >> 2) + 4 * q + (j & 3);
        if (m < 10) {
            if (ko < 25)       v = Wout[(a*15 + m)*25 + ko];
            else if (ko == 25) v = bout[a*15 + m];
        }
    }
    frag[(size_t)f * 512 + lane * 8 + j] = (_Float16)v;
}

__global__ __launch_bounds__(512) void actor_mfma(
    const float* __restrict__ spatial,
    const _Float16* __restrict__ frag,
    float* __restrict__ out)
{
    __shared__ _Float16 lds_f[FRAG_HALFS];     // 21504 B, block-shared constants
    __shared__ float    lds_o[NWAVES * 144];   // per-wave output compaction

    const int t = threadIdx.x;
    const int lane = t & 63, w = t >> 6;
    const int q = lane >> 4, e = lane & 15;
    const size_t b0 = (size_t)blockIdx.x * (16 * NWAVES * TPB);

    // ---- cooperative frag staging: 1344 float4, once per block
    {
        const float4* gf = (const float4*)frag;
        float4* df = (float4*)lds_f;
        #pragma unroll
        for (int k = 0; k < 3; ++k) {
            int idx = t + k * 512;
            if (idx < 1344) df[idx] = gf[idx];
        }
    }

    const float* sbase = spatial + (b0 + (size_t)(w * 16 + e)) * 27 + 8 * q;
    float* const ldso = lds_o + w * 144;
    const floatx4 z = {0.f, 0.f, 0.f, 0.f};

    __syncthreads();

    // 32-bit LDS half8-index; opaquely re-pinned per actor so the 21
    // loop-invariant ds_reads can't be hoisted into (and spill) registers.
    int fo = lane;

    union H8u { half8 v; fp16x2 p[4]; };

    // load one tile's spatial row-slice and pack straight to f16
    auto loadPack = [&](H8u& d, int tt) {
        const float* s_ = sbase + (size_t)tt * (16 * NWAVES * 27);
        float tmp[8];
        #pragma unroll
        for (int j = 0; j < 8; ++j) {
            int k = 8 * q + j;
            float v = (k == 27) ? 1.f : 0.f;   // bias slot; k>27 -> 0
            if (k < 27) v = s_[j];
            tmp[j] = v;
        }
        #pragma unroll
        for (int p_ = 0; p_ < 4; ++p_)
            d.p[p_] = __builtin_amdgcn_cvt_pkrtz(tmp[2*p_], tmp[2*p_+1]);
    };

    auto ss = [](float v_) {
        return v_ * __builtin_amdgcn_rcpf(1.0f + __builtin_fabsf(v_));
    };

    auto epilogue = [&](const floatx4 (&oacc)[3], int tt) {
        // softmax over actors of ch9, weighted sum of ch0..8
        const int src9 = 32 + e;   // lane (e, q=2); its reg1 = ch9
        float g0 = __shfl(oacc[0][1], src9, 64);
        float g1 = __shfl(oacc[1][1], src9, 64);
        float g2 = __shfl(oacc[2][1], src9, 64);
        float mx = fmaxf(g0, fmaxf(g1, g2));
        float e0 = __expf(g0 - mx);
        float e1 = __expf(g1 - mx);
        float e2 = __expf(g2 - mx);
        float inv = __builtin_amdgcn_rcpf(e0 + e1 + e2);
        e0 *= inv; e1 *= inv; e2 *= inv;

        float res[4];
        #pragma unroll
        for (int r = 0; r < 4; ++r)
            res[r] = oacc[0][r] * e0 + oacc[1][r] * e1 + oacc[2][r] * e2;

        // compact to this wave's scratch, coalesced float4 store
        if (q < 2) {
            #pragma unroll
            for (int r = 0; r < 4; ++r) ldso[e * 9 + 4 * q + r] = res[r];
        } else if (q == 2) {
            ldso[e * 9 + 8] = res[0];
        }
        // same-wave DS ordering: writes retire before the reads below issue
        if (lane < 36) {
            float4 v = *(const float4*)(ldso + lane * 4);
            *(float4*)(out + (b0 + (size_t)tt * (16 * NWAVES) + w * 16) * 9 + lane * 4) = v;
        }
    };

    // ---- paired-tile compute: one frag read set feeds two tile chains
    auto pairCompute = [&](int ta, int tb) {
        H8u BsA, BsB;
        loadPack(BsA, ta);
        loadPack(BsB, tb);

        floatx4 oaccA[3], oaccB[3];
        #pragma unroll
        for (int a = 0; a < 3; ++a) {
            asm volatile("" : "+v"(fo));   // opaque: blocks LICM/clustering
            const half8* fp = (const half8*)lds_f + fo;
            const int fb = a * 7;

            // stage1 low half (frags 0,2 shared by both tiles)
            H8u PA, PB;
            {
                half8 f0 = fp[(fb+0)*64], f2 = fp[(fb+2)*64];
                floatx4 MA0 = __builtin_amdgcn_mfma_f32_16x16x32_f16(f0, BsA.v, z, 0,0,0);
                floatx4 NA0 = __builtin_amdgcn_mfma_f32_16x16x32_f16(f2, BsA.v, z, 0,0,0);
                floatx4 MB0 = __builtin_amdgcn_mfma_f32_16x16x32_f16(f0, BsB.v, z, 0,0,0);
                floatx4 NB0 = __builtin_amdgcn_mfma_f32_16x16x32_f16(f2, BsB.v, z, 0,0,0);
                PA.p[0] = __builtin_amdgcn_cvt_pkrtz(MA0[0]*NA0[0], MA0[1]*NA0[1]);
                PA.p[1] = __builtin_amdgcn_cvt_pkrtz(MA0[2]*NA0[2], MA0[3]*NA0[3]);
                PB.p[0] = __builtin_amdgcn_cvt_pkrtz(MB0[0]*NB0[0], MB0[1]*NB0[1]);
                PB.p[1] = __builtin_amdgcn_cvt_pkrtz(MB0[2]*NB0[2], MB0[3]*NB0[3]);
            }
            // stage1 high half (frags 1,3); sigma slot kc=25 (q=2, elem 5)
            // carries the stage2 bias column -> force 1.0
            {
                half8 f1 = fp[(fb+1)*64], f3 = fp[(fb+3)*64];
                floatx4 MA1 = __builtin_amdgcn_mfma_f32_16x16x32_f16(f1, BsA.v, z, 0,0,0);
                floatx4 NA1 = __builtin_amdgcn_mfma_f32_16x16x32_f16(f3, BsA.v, z, 0,0,0);
                floatx4 MB1 = __builtin_amdgcn_mfma_f32_16x16x32_f16(f1, BsB.v, z, 0,0,0);
                floatx4 NB1 = __builtin_amdgcn_mfma_f32_16x16x32_f16(f3, BsB.v, z, 0,0,0);
                float gA5 = (q == 2) ? 1.f : MA1[1]*NA1[1];
                float gB5 = (q == 2) ? 1.f : MB1[1]*NB1[1];
                PA.p[2] = __builtin_amdgcn_cvt_pkrtz(MA1[0]*NA1[0], gA5);
                PA.p[3] = __builtin_amdgcn_cvt_pkrtz(MA1[2]*NA1[2], MA1[3]*NA1[3]);
                PB.p[2] = __builtin_amdgcn_cvt_pkrtz(MB1[0]*NB1[0], gB5);
                PB.p[3] = __builtin_amdgcn_cvt_pkrtz(MB1[2]*NB1[2], MB1[3]*NB1[3]);
            }

            // stage2 (frags 4,5 shared)
            H8u HhA, HhB;
            {
                half8 f4 = fp[(fb+4)*64], f5 = fp[(fb+5)*64];
                floatx4 HA0 = __builtin_amdgcn_mfma_f32_16x16x32_f16(f4, PA.v, z, 0,0,0);
                floatx4 HA1 = __builtin_amdgcn_mfma_f32_16x16x32_f16(f5, PA.v, z, 0,0,0);
                floatx4 HB0 = __builtin_amdgcn_mfma_f32_16x16x32_f16(f4, PB.v, z, 0,0,0);
                floatx4 HB1 = __builtin_amdgcn_mfma_f32_16x16x32_f16(f5, PB.v, z, 0,0,0);
                HhA.p[0] = __builtin_amdgcn_cvt_pkrtz(ss(HA0[0]), ss(HA0[1]));
                HhA.p[1] = __builtin_amdgcn_cvt_pkrtz(ss(HA0[2]), ss(HA0[3]));
                float hA5 = (q == 2) ? 1.f : ss(HA1[1]);
                HhA.p[2] = __builtin_amdgcn_cvt_pkrtz(ss(HA1[0]), hA5);
                HhA.p[3] = __builtin_amdgcn_cvt_pkrtz(ss(HA1[2]), ss(HA1[3]));
                HhB.p[0] = __builtin_amdgcn_cvt_pkrtz(ss(HB0[0]), ss(HB0[1]));
                HhB.p[1] = __builtin_amdgcn_cvt_pkrtz(ss(HB0[2]), ss(HB0[3]));
                float hB5 = (q == 2) ? 1.f : ss(HB1[1]);
                HhB.p[2] = __builtin_amdgcn_cvt_pkrtz(ss(HB1[0]), hB5);
                HhB.p[3] = __builtin_amdgcn_cvt_pkrtz(ss(HB1[2]), ss(HB1[3]));
            }

            // stage3 (frag 6 shared); lane (e,q) reg r holds ch = 4q+r
            {
                half8 f6 = fp[(fb+6)*64];
                oaccA[a] = __builtin_amdgcn_mfma_f32_16x16x32_f16(f6, HhA.v, z, 0,0,0);
                oaccB[a] = __builtin_amdgcn_mfma_f32_16x16x32_f16(f6, HhB.v, z, 0,0,0);
            }
        }

        epilogue(oaccA, ta);
        epilogue(oaccB, tb);
    };

    pairCompute(0, 1);
    pairCompute(2, 3);
}

extern "C" void kernel_launch(void* const* d_in, const int* in_sizes, int n_in,
                              void* d_out, int out_size, void* d_ws, size_t ws_size,
                              hipStream_t stream) {
    const float* spatial = (const float*)d_in[0];
    // d_in[1] = car_stats: unused by the model, never read.
    const float* Wmx  = (const float*)d_in[2];
    const float* bmx  = (const float*)d_in[3];
    const float* Wnx  = (const float*)d_in[4];
    const float* bnx  = (const float*)d_in[5];
    const float* Wmy  = (const float*)d_in[6];
    const float* bmy  = (const float*)d_in[7];
    const float* Wny  = (const float*)d_in[8];
    const float* bny  = (const float*)d_in[9];
    const float* Wmz  = (const float*)d_in[10];
    const float* bmz  = (const float*)d_in[11];
    const float* Wnz  = (const float*)d_in[12];
    const float* bnz  = (const float*)d_in[13];
    const float* Wlin = (const float*)d_in[14];
    const float* blin = (const float*)d_in[15];
    const float* Wout = (const float*)d_in[16];
    const float* bout = (const float*)d_in[17];
    float* out = (float*)d_out;

    _Float16* frag = (_Float16*)d_ws;   // 21504 B

    prep_frags<<<dim3(42), dim3(256), 0, stream>>>(
        Wmx, bmx, Wnx, bnx, Wmy, bmy, Wny, bny, Wmz, bmz, Wnz, bnz,
        Wlin, blin, Wout, bout, frag);

    const int nb = in_sizes[0] / 27;           // 1048576, multiple of 16*NWAVES*TPB
    dim3 grid(nb / (16 * NWAVES * TPB));       // 2048 blocks, 8 waves each
    actor_mfma<<<grid, dim3(64 * NWAVES), 0, stream>>>(spatial, frag, out);
}